// Round 7
// baseline (44826.889 us; speedup 1.0000x reference)
//
#include <hip/hip_runtime.h>

#define NTOT   2048
#define BATCH  32
#define TSTEPS 500
#define CAP    320               // CSR capacity/col (nnz ~ Binom(2048,0.1): max ~265)
#define RELEMS (BATCH * NTOT)    // 65536
#define OUT_BASE (TSTEPS * RELEMS)
#define NGRP   64                // barrier groups (G multiple of 64 for all candidates)
#define GLOBI  1024              // global counter slot; group g at bar[16*g]

static __device__ __forceinline__ float act(float u) {
  return 1.0f / (1.0f + expf(2.0f - 3.0f * u));   // sigmoid(3u-2), round-5-validated
}

__global__ void alif_init(unsigned int* bar) {
  for (int j = threadIdx.x; j < 2048; j += 256) bar[j] = 0u;
}

extern __shared__ unsigned char dynls[];           // uint2 csr[cpb][CAP]

__global__ __launch_bounds__(256, 8) void alif_main(
    const float* __restrict__ u0,
    const float* __restrict__ ext,
    const float* __restrict__ wrec,
    const float* __restrict__ mask,
    const float* __restrict__ sign,
    const float* __restrict__ dtv,
    float* __restrict__ rbuf,            // [2][NTOT][BATCH] f32 (transposed r)
    float* __restrict__ usave,           // d_out (f32)
    unsigned int* __restrict__ bar,
    int cpb, int lcpb) {                 // columns/block (power of 2), log2(cpb)
  uint2* csr = (uint2*)dynls;
  __shared__ float red[8][32];           // [group][batch] partials
  __shared__ int   wcnt[4];
  __shared__ int   nnzs[8];
  __shared__ int   maxns;

  const int tid  = threadIdx.x;
  const int lane = tid & 63;
  const int wv   = tid >> 6;

  // ---- build CSR once: all 4 waves cooperate per column (two-pass count+write) ----
  for (int clb = 0; clb < cpb; ++clb) {
    const int c = blockIdx.x * cpb + clb;
    const float* __restrict__ mrow = mask + c * NTOT;
    int cnt = 0;
    for (int k0 = wv * 512; k0 < wv * 512 + 512; k0 += 64)
      cnt += __popcll(__ballot(mrow[k0 + lane] != 0.0f));
    if (lane == 0) wcnt[wv] = cnt;
    __syncthreads();
    int base = 0;
    for (int w2 = 0; w2 < wv; ++w2) base += wcnt[w2];
    const int total = wcnt[0] + wcnt[1] + wcnt[2] + wcnt[3];
    for (int k0 = wv * 512; k0 < wv * 512 + 512; k0 += 64) {
      const int k = k0 + lane;
      const float mv = mrow[k];
      const bool nz = (mv != 0.0f);
      const unsigned long long bal = __ballot(nz);
      if (nz) {
        const int pos = base + __popcll(bal & ((1ull << lane) - 1ull));
        const float w = mv * fmaxf(wrec[c * NTOT + k], 0.0f) * sign[k];  // exact f32
        if (pos < CAP) csr[clb * CAP + pos] = make_uint2(__float_as_uint(w), (unsigned)(k * BATCH));
      }
      base += __popcll(bal);
    }
    if (tid == 0) nnzs[clb] = (total < CAP) ? total : CAP;
    __syncthreads();                     // wcnt reuse + nnzs visibility
  }
  const int S = 8 >> lcpb;               // k-slices per column
  if (tid == 0) {
    int m = 0;
    for (int i = 0; i < cpb; ++i) m = (nnzs[i] > m) ? nnzs[i] : m;
    maxns = (m + 4 * S - 1) & ~(4 * S - 1);   // pad: L = maxn/S multiple of 4
  }
  __syncthreads();
  const int maxn = maxns;
  for (int clb = 0; clb < cpb; ++clb)    // zero-pad: fmaf(r,0,acc) exact no-op
    for (int i = nnzs[clb] + tid; i < maxn; i += 256)
      csr[clb * CAP + i] = make_uint2(0u, 0u);
  // pad-writes ordered before first use by the t=0 barrier's __syncthreads

  // ---- thread roles: group = k-slice s of local column cl; s==0 owns (b,c) state ----
  const int grp = tid >> 5;              // 0..7
  const int b   = tid & 31;
  const int cl  = grp & (cpb - 1);
  const int s   = grp >> lcpb;
  const int c   = blockIdx.x * cpb + cl;
  const int L   = maxn >> (3 - lcpb);    // maxn / S
  const uint2* __restrict__ ce = csr + cl * CAP + s * L;
  const bool own = (s == 0);

  float u = 0.f, dtc = 0.f, omd = 0.f;
  if (own) {
    dtc = dtv[c];
    omd = 1.0f - dtc;
    u = u0[b * NTOT + c];
    rbuf[c * BATCH + b] = act(u);        // r_0 -> phase 0
  }
  const int g = blockIdx.x & (NGRP - 1);
  const unsigned grpsz = gridDim.x >> 6; // blocks per barrier group (pow2)

  for (int t = 0; t < TSTEPS; ++t) {
    // ---- grid barrier: publish r[t] (two-level, monotonic; round-5-validated fences) ----
    __syncthreads();                      // drains each wave's stores (vmcnt 0)
    if (tid == 0) {
      __threadfence();                    // release: wb to coherence point
      const unsigned prev =
          __hip_atomic_fetch_add(&bar[16 * g], 1u, __ATOMIC_ACQ_REL, __HIP_MEMORY_SCOPE_AGENT);
      if (((prev + 1u) & (grpsz - 1u)) == 0u)
        __hip_atomic_fetch_add(&bar[GLOBI], 1u, __ATOMIC_ACQ_REL, __HIP_MEMORY_SCOPE_AGENT);
      const unsigned gt = (unsigned)(t + 1) * NGRP;
      while (__hip_atomic_load(&bar[GLOBI], __ATOMIC_RELAXED, __HIP_MEMORY_SCOPE_AGENT) < gt)
        __builtin_amdgcn_s_sleep(1);
      __threadfence();                    // acquire: inv stale lines before reading r
    }
    __syncthreads();

    // ext (only owners consume it; hidden under the dot)
    const float e = own ? ext[t * RELEMS + b * NTOT + c] : 0.0f;

    // ---- exact-f32 sparse dot, slice s: csr entry broadcast to 32 lanes,
    //      gather rbuf[k*32+b] = one 128 B line per 32-thread group ----
    const float* __restrict__ rrow = rbuf + (t & 1) * RELEMS + b;
    float a0 = 0.f, a1 = 0.f, a2 = 0.f, a3 = 0.f;
    for (int i = 0; i < L; i += 4) {
      const uint2 e0 = ce[i], e1 = ce[i + 1], e2 = ce[i + 2], e3 = ce[i + 3];
      a0 = fmaf(rrow[e0.y], __uint_as_float(e0.x), a0);
      a1 = fmaf(rrow[e1.y], __uint_as_float(e1.x), a1);
      a2 = fmaf(rrow[e2.y], __uint_as_float(e2.x), a2);
      a3 = fmaf(rrow[e3.y], __uint_as_float(e3.x), a3);
    }
    red[grp][b] = (a0 + a1) + (a2 + a3);
    __syncthreads();

    // ---- epilogue (owners): cross-slice reduce + leaky integration ----
    if (own) {
      float rec = 0.f;
      for (int j = cl; j < 8; j += cpb) rec += red[j][b];
      const float drv = (rec + 0.5f) + e;
      u = u * omd + drv * dtc;
      usave[t * RELEMS + b * NTOT + c] = u;
      rbuf[((t + 1) & 1) * RELEMS + c * BATCH + b] = act(u);
    }
    // red[] WAR protected by next iteration's barrier __syncthreads
  }
}

// ---- outsave[t][b][o] = act(u_t) @ wout, u_t = (t==0 ? u0 : usave[t-1]) ----
__global__ __launch_bounds__(256) void alif_readout(
    const float* __restrict__ u0,
    const float* __restrict__ usave,
    const float* __restrict__ wout,
    float* __restrict__ outs) {
  const int wg = blockIdx.x * 4 + (threadIdx.x >> 6);   // 0..15999 = (t,b)
  const int lane = threadIdx.x & 63;
  const int t = wg >> 5, b = wg & 31;
  float a0 = 0.f, a1 = 0.f;
  for (int k0 = 0; k0 < NTOT; k0 += 64) {
    const int k = k0 + lane;
    const float uv = (t == 0) ? u0[b * NTOT + k] : usave[(t - 1) * RELEMS + b * NTOT + k];
    const float r = act(uv);
    const float2 w2 = *(const float2*)(wout + k * 2);
    a0 = fmaf(r, w2.x, a0);
    a1 = fmaf(r, w2.y, a1);
  }
#pragma unroll
  for (int off = 32; off; off >>= 1) {
    a0 += __shfl_xor(a0, off, 64);
    a1 += __shfl_xor(a1, off, 64);
  }
  if (lane == 0) {
    outs[t * (BATCH * 2) + b * 2 + 0] = a0;
    outs[t * (BATCH * 2) + b * 2 + 1] = a1;
  }
}

extern "C" void kernel_launch(void* const* d_in, const int* in_sizes, int n_in,
                              void* d_out, int out_size, void* d_ws, size_t ws_size,
                              hipStream_t stream) {
  const float* u0   = (const float*)d_in[0];
  const float* ext  = (const float*)d_in[1];
  const float* wrec = (const float*)d_in[2];
  const float* mask = (const float*)d_in[3];
  const float* sign = (const float*)d_in[4];
  const float* wout = (const float*)d_in[5];
  const float* dtv  = (const float*)d_in[6];
  float* out = (float*)d_out;

  char* w = (char*)d_ws;
  unsigned int* bar  = (unsigned int*)w;                 // 8 KB (2048 words, striped)
  float*        rbuf = (float*)(w + 8192);               // 2*65536*4 = 512 KB

  alif_init<<<dim3(1), dim3(256), 0, stream>>>(bar);

  // ---- adaptive cooperative grid: largest G the occupancy API certifies ----
  int cpb = 8, G = 256;                                  // guaranteed fallback (round-5 class)
  const int cand[3] = {1, 2, 4};
  for (int i = 0; i < 3; ++i) {
    const int c2 = cand[i];
    const int g2 = NTOT / c2;
    const int need = (g2 + 255) / 256;                   // blocks/CU needed (256 CUs)
    int nb = 0;
    if (hipOccupancyMaxActiveBlocksPerMultiprocessor(
            &nb, alif_main, 256, (size_t)c2 * CAP * sizeof(uint2)) == hipSuccess &&
        nb >= need) {
      cpb = c2; G = g2; break;
    }
  }

  int lcpb = __builtin_ctz((unsigned)cpb);
  for (;;) {
    void* args[] = {(void*)&u0, (void*)&ext, (void*)&wrec, (void*)&mask, (void*)&sign,
                    (void*)&dtv, (void*)&rbuf, (void*)&out, (void*)&bar,
                    (void*)&cpb, (void*)&lcpb};
    hipError_t err = hipLaunchCooperativeKernel(
        (const void*)alif_main, dim3(G), dim3(256), args,
        (uint32_t)((size_t)cpb * CAP * sizeof(uint2)), stream);
    if (err == hipSuccess || cpb == 8) break;            // cpb==8/G=256 is the known-good floor
    cpb *= 2; G /= 2; lcpb = __builtin_ctz((unsigned)cpb);
  }

  alif_readout<<<dim3(TSTEPS * BATCH / 4), dim3(256), 0, stream>>>(
      u0, out, wout, out + OUT_BASE);
}

// Round 8
// 11515.486 us; speedup vs baseline: 3.8927x; 3.8927x over previous
//
#include <hip/hip_runtime.h>

#define NTOT   2048
#define BATCH  32
#define TSTEPS 500
#define NBLK   256               // 1 block/CU — proven fence/barrier scale (round 5)
#define COLS   8                 // columns per block
#define CAP    320               // CSR capacity/col (nnz ~ Binom(2048,0.1): max ~265)
#define RELEMS (BATCH * NTOT)    // 65536
#define OUT_BASE (TSTEPS * RELEMS)
#define NGRP   8                 // barrier groups of 32 blocks (round-5 constants)
#define GRPSZ  32
#define GLOBI  128               // global counter slot; group g at bar[16*g]

static __device__ __forceinline__ float act(float u) {
  return 1.0f / (1.0f + expf(2.0f - 3.0f * u));   // sigmoid(3u-2), round-5-validated
}

__global__ void alif_init(unsigned int* bar) { bar[threadIdx.x] = 0u; }  // 256 words

__global__ __launch_bounds__(1024, 4) void alif_main(
    const float* __restrict__ u0,
    const float* __restrict__ ext,
    const float* __restrict__ wrec,
    const float* __restrict__ mask,
    const float* __restrict__ sign,
    const float* __restrict__ dtv,
    float* __restrict__ rbuf,            // [2][NTOT][BATCH] f32 (transposed r)
    float* __restrict__ usave,           // d_out (f32)
    unsigned int* __restrict__ bar) {
  const int tid  = threadIdx.x;
  const int lane = tid & 63;
  const int wv   = tid >> 6;
  const int nw   = blockDim.x >> 6;      // 16 (or 4 in fallback)
  const int KR   = NTOT / nw;            // k-range per wave in CSR build

  __shared__ uint2 csr[COLS * CAP];      // 20 KB: (.x = f32 weight bits, .y = k*BATCH)
  __shared__ float red[32][32];          // [group][batch] partials (4 KB)
  __shared__ int   wcnt[16];
  __shared__ int   nnzs[COLS];
  __shared__ int   maxns;

  // ---- build CSR once: all waves cooperate per column (two-pass count+write) ----
  for (int clb = 0; clb < COLS; ++clb) {
    const int c = blockIdx.x * COLS + clb;
    const float* __restrict__ mrow = mask + c * NTOT;
    int cnt = 0;
    for (int k0 = wv * KR; k0 < wv * KR + KR; k0 += 64)
      cnt += __popcll(__ballot(mrow[k0 + lane] != 0.0f));
    if (lane == 0) wcnt[wv] = cnt;
    __syncthreads();
    int base = 0, total = 0;
    for (int w2 = 0; w2 < nw; ++w2) {
      if (w2 < wv) base += wcnt[w2];
      total += wcnt[w2];
    }
    for (int k0 = wv * KR; k0 < wv * KR + KR; k0 += 64) {
      const int k = k0 + lane;
      const float mv = mrow[k];
      const bool nz = (mv != 0.0f);
      const unsigned long long bal = __ballot(nz);
      if (nz) {
        const int pos = base + __popcll(bal & ((1ull << lane) - 1ull));
        const float w = mv * fmaxf(wrec[c * NTOT + k], 0.0f) * sign[k];  // exact f32
        if (pos < CAP) csr[clb * CAP + pos] = make_uint2(__float_as_uint(w), (unsigned)(k * BATCH));
      }
      base += __popcll(bal);
    }
    if (tid == 0) nnzs[clb] = (total < CAP) ? total : CAP;
    __syncthreads();                     // wcnt reuse + nnzs visibility
  }
  if (tid == 0) {
    int m = 0;
    for (int i = 0; i < COLS; ++i) m = (nnzs[i] > m) ? nnzs[i] : m;
    maxns = (m + 31) & ~31;              // L divisible by 8 for S in {1,4}
  }
  __syncthreads();
  const int maxn = maxns;
  for (int clb = 0; clb < COLS; ++clb)   // zero-pad: fmaf(r,0,acc) exact no-op
    for (int i = nnzs[clb] + tid; i < maxn; i += blockDim.x)
      csr[clb * CAP + i] = make_uint2(0u, 0u);
  // pad-writes ordered before first use by the t=0 barrier's __syncthreads

  // ---- roles: group = (slice s, local col cl); s==0 threads own (b,c) state ----
  const int grp = tid >> 5;              // 0..31 (0..7 in fallback)
  const int b   = tid & 31;
  const int cl  = grp & 7;
  const int s   = grp >> 3;              // 0..S-1
  const int S   = blockDim.x >> 8;       // 4 (or 1)
  const int lS  = 31 - __clz((unsigned)S);
  const int c   = blockIdx.x * COLS + cl;
  const int L   = maxn >> lS;
  const uint2* __restrict__ ce = csr + cl * CAP + s * L;
  const bool own = (s == 0);

  float u = 0.f, dtc = 0.f, omd = 0.f;
  if (own) {
    dtc = dtv[c];
    omd = 1.0f - dtc;
    u = u0[b * NTOT + c];
    rbuf[c * BATCH + b] = act(u);        // r_0 -> phase 0
  }
  const int g = blockIdx.x & (NGRP - 1);

  for (int t = 0; t < TSTEPS; ++t) {
    // ---- grid barrier: publish r[t] (round-5-proven two-level, 256 arrivals) ----
    __syncthreads();
    if (tid == 0) {
      __threadfence();                    // release: wb to coherence point
      const unsigned prev =
          __hip_atomic_fetch_add(&bar[16 * g], 1u, __ATOMIC_ACQ_REL, __HIP_MEMORY_SCOPE_AGENT);
      if (((prev + 1u) & (GRPSZ - 1u)) == 0u)
        __hip_atomic_fetch_add(&bar[GLOBI], 1u, __ATOMIC_ACQ_REL, __HIP_MEMORY_SCOPE_AGENT);
      const unsigned gt = (unsigned)(t + 1) * NGRP;
      while (__hip_atomic_load(&bar[GLOBI], __ATOMIC_RELAXED, __HIP_MEMORY_SCOPE_AGENT) < gt)
        __builtin_amdgcn_s_sleep(1);
      __threadfence();                    // acquire: inv stale lines before reading r
    }
    __syncthreads();

    // ext (owners only; consumed in epilogue — hidden under the dot)
    const float e = own ? ext[t * RELEMS + b * NTOT + c] : 0.0f;

    // ---- exact-f32 sparse dot, slice s: csr broadcast to 32 lanes,
    //      gather rbuf[k*32+b] = one 128 B line per 32-thread group ----
    const float* __restrict__ rrow = rbuf + (t & 1) * RELEMS + b;
    float a0 = 0.f, a1 = 0.f, a2 = 0.f, a3 = 0.f;
    float a4 = 0.f, a5 = 0.f, a6 = 0.f, a7 = 0.f;
    for (int i = 0; i < L; i += 8) {
      const uint2 e0 = ce[i],     e1 = ce[i + 1], e2 = ce[i + 2], e3 = ce[i + 3];
      const uint2 e4 = ce[i + 4], e5 = ce[i + 5], e6 = ce[i + 6], e7 = ce[i + 7];
      a0 = fmaf(rrow[e0.y], __uint_as_float(e0.x), a0);
      a1 = fmaf(rrow[e1.y], __uint_as_float(e1.x), a1);
      a2 = fmaf(rrow[e2.y], __uint_as_float(e2.x), a2);
      a3 = fmaf(rrow[e3.y], __uint_as_float(e3.x), a3);
      a4 = fmaf(rrow[e4.y], __uint_as_float(e4.x), a4);
      a5 = fmaf(rrow[e5.y], __uint_as_float(e5.x), a5);
      a6 = fmaf(rrow[e6.y], __uint_as_float(e6.x), a6);
      a7 = fmaf(rrow[e7.y], __uint_as_float(e7.x), a7);
    }
    red[grp][b] = (((a0 + a1) + (a2 + a3)) + ((a4 + a5) + (a6 + a7)));
    __syncthreads();

    // ---- epilogue (owners): cross-slice reduce + leaky integration ----
    if (own) {
      float rec = 0.f;
      for (int j = 0; j < S; ++j) rec += red[cl + 8 * j][b];
      const float drv = (rec + 0.5f) + e;
      u = u * omd + drv * dtc;
      rbuf[((t + 1) & 1) * RELEMS + c * BATCH + b] = act(u);   // critical-path store first
      usave[t * RELEMS + b * NTOT + c] = u;
    }
    // red[] WAR protected by next iteration's barrier __syncthreads
  }
}

// ---- outsave[t][b][o] = act(u_t) @ wout, u_t = (t==0 ? u0 : usave[t-1]) ----
__global__ __launch_bounds__(256) void alif_readout(
    const float* __restrict__ u0,
    const float* __restrict__ usave,
    const float* __restrict__ wout,
    float* __restrict__ outs) {
  const int wg = blockIdx.x * 4 + (threadIdx.x >> 6);   // 0..15999 = (t,b)
  const int lane = threadIdx.x & 63;
  const int t = wg >> 5, b = wg & 31;
  float a0 = 0.f, a1 = 0.f;
  for (int k0 = 0; k0 < NTOT; k0 += 64) {
    const int k = k0 + lane;
    const float uv = (t == 0) ? u0[b * NTOT + k] : usave[(t - 1) * RELEMS + b * NTOT + k];
    const float r = act(uv);
    const float2 w2 = *(const float2*)(wout + k * 2);
    a0 = fmaf(r, w2.x, a0);
    a1 = fmaf(r, w2.y, a1);
  }
#pragma unroll
  for (int off = 32; off; off >>= 1) {
    a0 += __shfl_xor(a0, off, 64);
    a1 += __shfl_xor(a1, off, 64);
  }
  if (lane == 0) {
    outs[t * (BATCH * 2) + b * 2 + 0] = a0;
    outs[t * (BATCH * 2) + b * 2 + 1] = a1;
  }
}

extern "C" void kernel_launch(void* const* d_in, const int* in_sizes, int n_in,
                              void* d_out, int out_size, void* d_ws, size_t ws_size,
                              hipStream_t stream) {
  const float* u0   = (const float*)d_in[0];
  const float* ext  = (const float*)d_in[1];
  const float* wrec = (const float*)d_in[2];
  const float* mask = (const float*)d_in[3];
  const float* sign = (const float*)d_in[4];
  const float* wout = (const float*)d_in[5];
  const float* dtv  = (const float*)d_in[6];
  float* out = (float*)d_out;

  char* w = (char*)d_ws;
  unsigned int* bar  = (unsigned int*)w;                 // 1 KB (slots 16g, 128)
  float*        rbuf = (float*)(w + 1024);               // 2*65536*4 = 512 KB

  alif_init<<<dim3(1), dim3(256), 0, stream>>>(bar);

  void* args[] = {(void*)&u0, (void*)&ext, (void*)&wrec, (void*)&mask, (void*)&sign,
                  (void*)&dtv, (void*)&rbuf, (void*)&out, (void*)&bar};

  // 256 blocks x 1024 threads (1 block/CU). Error-checked; fallback = round-5 config.
  hipError_t err = hipLaunchCooperativeKernel((const void*)alif_main, dim3(NBLK),
                                              dim3(1024), args, 0, stream);
  if (err != hipSuccess) {
    (void)hipLaunchCooperativeKernel((const void*)alif_main, dim3(NBLK),
                                     dim3(256), args, 0, stream);
  }

  alif_readout<<<dim3(TSTEPS * BATCH / 4), dim3(256), 0, stream>>>(
      u0, out, wout, out + OUT_BASE);
}

// Round 9
// 3490.313 us; speedup vs baseline: 12.8432x; 3.2993x over previous
//
#include <hip/hip_runtime.h>

#define NTOT   2048
#define BATCH  32
#define TSTEPS 500
#define NBLK   256               // 1 block/CU — proven launch/barrier scale
#define COLS   8                 // columns per block
#define CAP    320               // CSR capacity/col (nnz ~ Binom(2048,0.1): max ~265)
#define RELEMS (BATCH * NTOT)    // 65536
#define OUT_BASE (TSTEPS * RELEMS)
#define NGRP   8                 // barrier groups of 32 blocks
#define GRPSZ  32
#define GLOBI  128               // global counter slot; group g at bar[16*g]

static __device__ __forceinline__ float act(float u) {
  return 1.0f / (1.0f + expf(2.0f - 3.0f * u));   // sigmoid(3u-2), round-5-validated
}

// Coherent (LLC-backed, never cache-stale) f32 access — NO wbl2/inv walks needed.
static __device__ __forceinline__ void st_coh(float* p, float v) {
  __hip_atomic_store(p, v, __ATOMIC_RELAXED, __HIP_MEMORY_SCOPE_AGENT);
}
static __device__ __forceinline__ float ld_coh(const float* p) {
  return __hip_atomic_load(p, __ATOMIC_RELAXED, __HIP_MEMORY_SCOPE_AGENT);
}

__global__ void alif_init(unsigned int* bar) { bar[threadIdx.x] = 0u; }  // 256 words

__global__ __launch_bounds__(1024, 4) void alif_main(
    const float* __restrict__ u0,
    const float* __restrict__ ext,
    const float* __restrict__ wrec,
    const float* __restrict__ mask,
    const float* __restrict__ sign,
    const float* __restrict__ dtv,
    float* __restrict__ rbuf,            // [2][NTOT][BATCH] f32 (transposed r, LLC-coherent)
    float* __restrict__ usave,           // d_out (f32)
    unsigned int* __restrict__ bar) {
  const int tid  = threadIdx.x;
  const int lane = tid & 63;
  const int wv   = tid >> 6;
  const int nw   = blockDim.x >> 6;      // 16 (or 4 in fallback)
  const int KR   = NTOT / nw;            // k-range per wave in CSR build

  __shared__ uint2 csr[COLS * CAP];      // 20 KB: (.x = f32 weight bits, .y = k*BATCH)
  __shared__ float red[32][32];          // [group][batch] partials (4 KB)
  __shared__ int   wcnt[16];
  __shared__ int   nnzs[COLS];
  __shared__ int   maxns;

  // ---- build CSR once: all waves cooperate per column (two-pass count+write) ----
  for (int clb = 0; clb < COLS; ++clb) {
    const int c = blockIdx.x * COLS + clb;
    const float* __restrict__ mrow = mask + c * NTOT;
    int cnt = 0;
    for (int k0 = wv * KR; k0 < wv * KR + KR; k0 += 64)
      cnt += __popcll(__ballot(mrow[k0 + lane] != 0.0f));
    if (lane == 0) wcnt[wv] = cnt;
    __syncthreads();
    int base = 0, total = 0;
    for (int w2 = 0; w2 < nw; ++w2) {
      if (w2 < wv) base += wcnt[w2];
      total += wcnt[w2];
    }
    for (int k0 = wv * KR; k0 < wv * KR + KR; k0 += 64) {
      const int k = k0 + lane;
      const float mv = mrow[k];
      const bool nz = (mv != 0.0f);
      const unsigned long long bal = __ballot(nz);
      if (nz) {
        const int pos = base + __popcll(bal & ((1ull << lane) - 1ull));
        const float w = mv * fmaxf(wrec[c * NTOT + k], 0.0f) * sign[k];  // exact f32
        if (pos < CAP) csr[clb * CAP + pos] = make_uint2(__float_as_uint(w), (unsigned)(k * BATCH));
      }
      base += __popcll(bal);
    }
    if (tid == 0) nnzs[clb] = (total < CAP) ? total : CAP;
    __syncthreads();                     // wcnt reuse + nnzs visibility
  }
  if (tid == 0) {
    int m = 0;
    for (int i = 0; i < COLS; ++i) m = (nnzs[i] > m) ? nnzs[i] : m;
    maxns = (m + 31) & ~31;              // L divisible by 8 for S in {1,4}
  }
  __syncthreads();
  const int maxn = maxns;
  for (int clb = 0; clb < COLS; ++clb)   // zero-pad: fmaf(r,0,acc) exact no-op
    for (int i = nnzs[clb] + tid; i < maxn; i += blockDim.x)
      csr[clb * CAP + i] = make_uint2(0u, 0u);
  // pad-writes ordered before first use by the t=0 barrier's __syncthreads

  // ---- roles: group = (slice s, local col cl); s==0 threads own (b,c) state ----
  const int grp = tid >> 5;              // 0..31 (0..7 in fallback)
  const int b   = tid & 31;
  const int cl  = grp & 7;
  const int s   = grp >> 3;              // 0..S-1
  const int S   = blockDim.x >> 8;       // 4 (or 1)
  const int lS  = 31 - __clz((unsigned)S);
  const int c   = blockIdx.x * COLS + cl;
  const int L   = maxn >> lS;
  const uint2* __restrict__ ce = csr + cl * CAP + s * L;
  const bool own = (s == 0);

  float u = 0.f, dtc = 0.f, omd = 0.f;
  if (own) {
    dtc = dtv[c];
    omd = 1.0f - dtc;
    u = u0[b * NTOT + c];
    st_coh(&rbuf[c * BATCH + b], act(u));   // r_0 -> phase 0, write-through to LLC
  }
  const int g = blockIdx.x & (NGRP - 1);

  for (int t = 0; t < TSTEPS; ++t) {
    // ---- grid barrier, ZERO cache maintenance:
    //      syncthreads drains vmcnt (sc-stores acked at LLC) before the arrival add;
    //      LLC serialization of {r-stores -> adds -> spin-load -> sc-gathers} gives
    //      release/acquire without any wbl2/inv walk. All atomics RELAXED. ----
    __syncthreads();
    if (tid == 0) {
      const unsigned prev =
          __hip_atomic_fetch_add(&bar[16 * g], 1u, __ATOMIC_RELAXED, __HIP_MEMORY_SCOPE_AGENT);
      if (((prev + 1u) & (GRPSZ - 1u)) == 0u)
        __hip_atomic_fetch_add(&bar[GLOBI], 1u, __ATOMIC_RELAXED, __HIP_MEMORY_SCOPE_AGENT);
      const unsigned gt = (unsigned)(t + 1) * NGRP;
      while (__hip_atomic_load(&bar[GLOBI], __ATOMIC_RELAXED, __HIP_MEMORY_SCOPE_AGENT) < gt)
        __builtin_amdgcn_s_sleep(1);
    }
    __syncthreads();

    // ext (owners only; consumed in epilogue — hidden under the dot)
    const float e = own ? ext[t * RELEMS + b * NTOT + c] : 0.0f;

    // ---- exact-f32 sparse dot, slice s: csr broadcast to 32 lanes,
    //      gather = coherent LLC loads (addresses from LDS -> fully pipelineable) ----
    const float* __restrict__ rrow = rbuf + (t & 1) * RELEMS + b;
    float a0 = 0.f, a1 = 0.f, a2 = 0.f, a3 = 0.f;
    float a4 = 0.f, a5 = 0.f, a6 = 0.f, a7 = 0.f;
    for (int i = 0; i < L; i += 8) {
      const uint2 e0 = ce[i],     e1 = ce[i + 1], e2 = ce[i + 2], e3 = ce[i + 3];
      const uint2 e4 = ce[i + 4], e5 = ce[i + 5], e6 = ce[i + 6], e7 = ce[i + 7];
      a0 = fmaf(ld_coh(rrow + e0.y), __uint_as_float(e0.x), a0);
      a1 = fmaf(ld_coh(rrow + e1.y), __uint_as_float(e1.x), a1);
      a2 = fmaf(ld_coh(rrow + e2.y), __uint_as_float(e2.x), a2);
      a3 = fmaf(ld_coh(rrow + e3.y), __uint_as_float(e3.x), a3);
      a4 = fmaf(ld_coh(rrow + e4.y), __uint_as_float(e4.x), a4);
      a5 = fmaf(ld_coh(rrow + e5.y), __uint_as_float(e5.x), a5);
      a6 = fmaf(ld_coh(rrow + e6.y), __uint_as_float(e6.x), a6);
      a7 = fmaf(ld_coh(rrow + e7.y), __uint_as_float(e7.x), a7);
    }
    red[grp][b] = (((a0 + a1) + (a2 + a3)) + ((a4 + a5) + (a6 + a7)));
    __syncthreads();

    // ---- epilogue (owners): cross-slice reduce + leaky integration ----
    if (own) {
      float rec = 0.f;
      for (int j = 0; j < S; ++j) rec += red[cl + 8 * j][b];
      const float drv = (rec + 0.5f) + e;
      u = u * omd + drv * dtc;
      st_coh(&rbuf[((t + 1) & 1) * RELEMS + c * BATCH + b], act(u));  // critical path
      usave[t * RELEMS + b * NTOT + c] = u;                           // plain store
    }
    // red[] WAR protected by next iteration's barrier __syncthreads
  }
}

// ---- outsave[t][b][o] = act(u_t) @ wout, u_t = (t==0 ? u0 : usave[t-1]) ----
__global__ __launch_bounds__(256) void alif_readout(
    const float* __restrict__ u0,
    const float* __restrict__ usave,
    const float* __restrict__ wout,
    float* __restrict__ outs) {
  const int wg = blockIdx.x * 4 + (threadIdx.x >> 6);   // 0..15999 = (t,b)
  const int lane = threadIdx.x & 63;
  const int t = wg >> 5, b = wg & 31;
  float a0 = 0.f, a1 = 0.f;
  for (int k0 = 0; k0 < NTOT; k0 += 64) {
    const int k = k0 + lane;
    const float uv = (t == 0) ? u0[b * NTOT + k] : usave[(t - 1) * RELEMS + b * NTOT + k];
    const float r = act(uv);
    const float2 w2 = *(const float2*)(wout + k * 2);
    a0 = fmaf(r, w2.x, a0);
    a1 = fmaf(r, w2.y, a1);
  }
#pragma unroll
  for (int off = 32; off; off >>= 1) {
    a0 += __shfl_xor(a0, off, 64);
    a1 += __shfl_xor(a1, off, 64);
  }
  if (lane == 0) {
    outs[t * (BATCH * 2) + b * 2 + 0] = a0;
    outs[t * (BATCH * 2) + b * 2 + 1] = a1;
  }
}

extern "C" void kernel_launch(void* const* d_in, const int* in_sizes, int n_in,
                              void* d_out, int out_size, void* d_ws, size_t ws_size,
                              hipStream_t stream) {
  const float* u0   = (const float*)d_in[0];
  const float* ext  = (const float*)d_in[1];
  const float* wrec = (const float*)d_in[2];
  const float* mask = (const float*)d_in[3];
  const float* sign = (const float*)d_in[4];
  const float* wout = (const float*)d_in[5];
  const float* dtv  = (const float*)d_in[6];
  float* out = (float*)d_out;

  char* w = (char*)d_ws;
  unsigned int* bar  = (unsigned int*)w;                 // 1 KB (slots 16g, 128)
  float*        rbuf = (float*)(w + 1024);               // 2*65536*4 = 512 KB

  alif_init<<<dim3(1), dim3(256), 0, stream>>>(bar);

  void* args[] = {(void*)&u0, (void*)&ext, (void*)&wrec, (void*)&mask, (void*)&sign,
                  (void*)&dtv, (void*)&rbuf, (void*)&out, (void*)&bar};

  // 256 blocks x 1024 threads (1 block/CU). Error-checked; fallback = 256-thread config.
  hipError_t err = hipLaunchCooperativeKernel((const void*)alif_main, dim3(NBLK),
                                              dim3(1024), args, 0, stream);
  if (err != hipSuccess) {
    (void)hipLaunchCooperativeKernel((const void*)alif_main, dim3(NBLK),
                                     dim3(256), args, 0, stream);
  }

  alif_readout<<<dim3(TSTEPS * BATCH / 4), dim3(256), 0, stream>>>(
      u0, out, wout, out + OUT_BASE);
}

// Round 10
// 2988.129 us; speedup vs baseline: 15.0017x; 1.1681x over previous
//
#include <hip/hip_runtime.h>

#define NTOT   2048
#define BATCH  32
#define TSTEPS 500
#define NBLK   256               // 1 block/CU — proven launch/barrier scale
#define COLS   8                 // columns per block
#define CAP    320               // CSR capacity/col (nnz ~ Binom(2048,0.1): max ~265)
#define RELEMS (BATCH * NTOT)    // 65536
#define OUT_BASE (TSTEPS * RELEMS)
#define NGRP   8                 // barrier groups of 32 blocks
#define GRPSZ  32
#define GLOBI  128               // global counter slot; group g at bar[16*g]

static __device__ __forceinline__ float act(float u) {
  return 1.0f / (1.0f + expf(2.0f - 3.0f * u));   // sigmoid(3u-2), round-5-validated
}

// Coherent (LLC-backed) access — producers always publish through LLC.
static __device__ __forceinline__ void st_coh(float* p, float v) {
  __hip_atomic_store(p, v, __ATOMIC_RELAXED, __HIP_MEMORY_SCOPE_AGENT);
}
static __device__ __forceinline__ float ld_coh(const float* p) {
  return __hip_atomic_load(p, __ATOMIC_RELAXED, __HIP_MEMORY_SCOPE_AGENT);
}

__global__ void alif_init(unsigned int* bar) { bar[threadIdx.x] = 0u; }  // 256 words

// FRESH=true: rbuf has TSTEPS+1 monotonically-advancing phases -> gather may use
// PLAIN CACHED loads (no stale line can exist; L2 serves ~36x reuse per XCD).
// FRESH=false: 2-phase rbuf, gather via agent loads (round-9 behavior).
template <bool FRESH>
__global__ __launch_bounds__(1024, 4) void alif_main(
    const float* __restrict__ u0,
    const float* __restrict__ ext,
    const float* __restrict__ wrec,
    const float* __restrict__ mask,
    const float* __restrict__ sign,
    const float* __restrict__ dtv,
    float* __restrict__ rbuf,            // [nph][NTOT][BATCH] f32 (transposed r)
    float* __restrict__ usave,           // d_out (f32)
    unsigned int* __restrict__ bar) {
  const int tid  = threadIdx.x;
  const int lane = tid & 63;
  const int wv   = tid >> 6;
  const int nw   = blockDim.x >> 6;      // 16 (or 4 in fallback)
  const int KR   = NTOT / nw;            // k-range per wave in CSR build

  __shared__ uint2 csr[COLS * CAP];      // 20 KB: (.x = f32 weight bits, .y = k*BATCH)
  __shared__ float red[32][32];          // [group][batch] partials (4 KB)
  __shared__ int   wcnt[16];
  __shared__ int   nnzs[COLS];
  __shared__ int   Lcol[COLS];           // per-column padded length (mult of 32)

  // ---- build CSR once: all waves cooperate per column (two-pass count+write) ----
  for (int clb = 0; clb < COLS; ++clb) {
    const int c = blockIdx.x * COLS + clb;
    const float* __restrict__ mrow = mask + c * NTOT;
    int cnt = 0;
    for (int k0 = wv * KR; k0 < wv * KR + KR; k0 += 64)
      cnt += __popcll(__ballot(mrow[k0 + lane] != 0.0f));
    if (lane == 0) wcnt[wv] = cnt;
    __syncthreads();
    int base = 0, total = 0;
    for (int w2 = 0; w2 < nw; ++w2) {
      if (w2 < wv) base += wcnt[w2];
      total += wcnt[w2];
    }
    for (int k0 = wv * KR; k0 < wv * KR + KR; k0 += 64) {
      const int k = k0 + lane;
      const float mv = mrow[k];
      const bool nz = (mv != 0.0f);
      const unsigned long long bal = __ballot(nz);
      if (nz) {
        const int pos = base + __popcll(bal & ((1ull << lane) - 1ull));
        const float w = mv * fmaxf(wrec[c * NTOT + k], 0.0f) * sign[k];  // exact f32
        if (pos < CAP) csr[clb * CAP + pos] = make_uint2(__float_as_uint(w), (unsigned)(k * BATCH));
      }
      base += __popcll(bal);
    }
    if (tid == 0) {
      const int nn = (total < CAP) ? total : CAP;
      nnzs[clb] = nn;
      Lcol[clb] = (nn + 31) & ~31;       // per-column pad (mult of 32 -> S*8 aligned)
    }
    __syncthreads();                     // wcnt reuse + nnzs/Lcol visibility
  }
  for (int clb = 0; clb < COLS; ++clb)   // zero-pad: fmaf(r,0,acc) exact no-op
    for (int i = nnzs[clb] + tid; i < Lcol[clb]; i += blockDim.x)
      csr[clb * CAP + i] = make_uint2(0u, 0u);
  // pad-writes ordered before first use by the t=0 barrier's __syncthreads

  // ---- roles: group = (slice s, local col cl); s==0 threads own (b,c) state ----
  const int grp = tid >> 5;              // 0..31 (0..7 in fallback)
  const int b   = tid & 31;
  const int cl  = grp & 7;
  const int s   = grp >> 3;              // 0..S-1
  const int S   = blockDim.x >> 8;       // 4 (or 1)
  const int lS  = 31 - __clz((unsigned)S);
  const int c   = blockIdx.x * COLS + cl;
  const bool own = (s == 0);

  float u = 0.f, dtc = 0.f, omd = 0.f;
  if (own) {
    dtc = dtv[c];
    omd = 1.0f - dtc;
    u = u0[b * NTOT + c];
    st_coh(&rbuf[c * BATCH + b], act(u));   // r_0 -> phase 0, write-through to LLC
  }
  const int g = blockIdx.x & (NGRP - 1);

  for (int t = 0; t < TSTEPS; ++t) {
    // ---- grid barrier, zero cache maintenance (round-9-proven) ----
    __syncthreads();
    if (tid == 0) {
      const unsigned prev =
          __hip_atomic_fetch_add(&bar[16 * g], 1u, __ATOMIC_RELAXED, __HIP_MEMORY_SCOPE_AGENT);
      if (((prev + 1u) & (GRPSZ - 1u)) == 0u)
        __hip_atomic_fetch_add(&bar[GLOBI], 1u, __ATOMIC_RELAXED, __HIP_MEMORY_SCOPE_AGENT);
      const unsigned gt = (unsigned)(t + 1) * NGRP;
      while (__hip_atomic_load(&bar[GLOBI], __ATOMIC_RELAXED, __HIP_MEMORY_SCOPE_AGENT) < gt)
        __builtin_amdgcn_s_sleep(1);
    }
    __syncthreads();

    // ext (owners only; consumed in epilogue — hidden under the dot)
    const float e = own ? ext[t * RELEMS + b * NTOT + c] : 0.0f;

    // ---- exact-f32 sparse dot, slice s; per-column exact trip count ----
    const int Lc = Lcol[cl] >> lS;       // slice length (mult of 8)
    const uint2* __restrict__ ce = csr + cl * CAP + s * Lc;
    const size_t rph = FRESH ? (size_t)t : (size_t)(t & 1);
    const float* __restrict__ rrow = rbuf + rph * RELEMS + b;
    float a0 = 0.f, a1 = 0.f, a2 = 0.f, a3 = 0.f;
    float a4 = 0.f, a5 = 0.f, a6 = 0.f, a7 = 0.f;
    for (int i = 0; i < Lc; i += 8) {
      const uint2 e0 = ce[i],     e1 = ce[i + 1], e2 = ce[i + 2], e3 = ce[i + 3];
      const uint2 e4 = ce[i + 4], e5 = ce[i + 5], e6 = ce[i + 6], e7 = ce[i + 7];
      if (FRESH) {                        // plain cached loads: L2-served (fresh region)
        a0 = fmaf(rrow[e0.y], __uint_as_float(e0.x), a0);
        a1 = fmaf(rrow[e1.y], __uint_as_float(e1.x), a1);
        a2 = fmaf(rrow[e2.y], __uint_as_float(e2.x), a2);
        a3 = fmaf(rrow[e3.y], __uint_as_float(e3.x), a3);
        a4 = fmaf(rrow[e4.y], __uint_as_float(e4.x), a4);
        a5 = fmaf(rrow[e5.y], __uint_as_float(e5.x), a5);
        a6 = fmaf(rrow[e6.y], __uint_as_float(e6.x), a6);
        a7 = fmaf(rrow[e7.y], __uint_as_float(e7.x), a7);
      } else {                            // 2-phase reuse: must stay LLC-coherent
        a0 = fmaf(ld_coh(rrow + e0.y), __uint_as_float(e0.x), a0);
        a1 = fmaf(ld_coh(rrow + e1.y), __uint_as_float(e1.x), a1);
        a2 = fmaf(ld_coh(rrow + e2.y), __uint_as_float(e2.x), a2);
        a3 = fmaf(ld_coh(rrow + e3.y), __uint_as_float(e3.x), a3);
        a4 = fmaf(ld_coh(rrow + e4.y), __uint_as_float(e4.x), a4);
        a5 = fmaf(ld_coh(rrow + e5.y), __uint_as_float(e5.x), a5);
        a6 = fmaf(ld_coh(rrow + e6.y), __uint_as_float(e6.x), a6);
        a7 = fmaf(ld_coh(rrow + e7.y), __uint_as_float(e7.x), a7);
      }
    }
    red[grp][b] = (((a0 + a1) + (a2 + a3)) + ((a4 + a5) + (a6 + a7)));
    __syncthreads();

    // ---- epilogue (owners): cross-slice reduce + leaky integration ----
    if (own) {
      float rec = 0.f;
      for (int j = 0; j < S; ++j) rec += red[cl + 8 * j][b];
      const float drv = (rec + 0.5f) + e;
      u = u * omd + drv * dtc;
      const size_t wph = FRESH ? (size_t)(t + 1) : (size_t)((t + 1) & 1);
      st_coh(&rbuf[wph * RELEMS + c * BATCH + b], act(u));  // publish via LLC
      usave[t * RELEMS + b * NTOT + c] = u;                 // plain store
    }
    // red[] WAR protected by next iteration's barrier __syncthreads
  }
}

// ---- outsave[t][b][o] = act(u_t) @ wout, u_t = (t==0 ? u0 : usave[t-1]) ----
__global__ __launch_bounds__(256) void alif_readout(
    const float* __restrict__ u0,
    const float* __restrict__ usave,
    const float* __restrict__ wout,
    float* __restrict__ outs) {
  const int wg = blockIdx.x * 4 + (threadIdx.x >> 6);   // 0..15999 = (t,b)
  const int lane = threadIdx.x & 63;
  const int t = wg >> 5, b = wg & 31;
  float a0 = 0.f, a1 = 0.f;
  for (int k0 = 0; k0 < NTOT; k0 += 64) {
    const int k = k0 + lane;
    const float uv = (t == 0) ? u0[b * NTOT + k] : usave[(t - 1) * RELEMS + b * NTOT + k];
    const float r = act(uv);
    const float2 w2 = *(const float2*)(wout + k * 2);
    a0 = fmaf(r, w2.x, a0);
    a1 = fmaf(r, w2.y, a1);
  }
#pragma unroll
  for (int off = 32; off; off >>= 1) {
    a0 += __shfl_xor(a0, off, 64);
    a1 += __shfl_xor(a1, off, 64);
  }
  if (lane == 0) {
    outs[t * (BATCH * 2) + b * 2 + 0] = a0;
    outs[t * (BATCH * 2) + b * 2 + 1] = a1;
  }
}

extern "C" void kernel_launch(void* const* d_in, const int* in_sizes, int n_in,
                              void* d_out, int out_size, void* d_ws, size_t ws_size,
                              hipStream_t stream) {
  const float* u0   = (const float*)d_in[0];
  const float* ext  = (const float*)d_in[1];
  const float* wrec = (const float*)d_in[2];
  const float* mask = (const float*)d_in[3];
  const float* sign = (const float*)d_in[4];
  const float* wout = (const float*)d_in[5];
  const float* dtv  = (const float*)d_in[6];
  float* out = (float*)d_out;

  char* w = (char*)d_ws;
  unsigned int* bar  = (unsigned int*)w;                 // 1 KB (slots 16g, 128)
  float*        rbuf = (float*)(w + 1024);

  const size_t need = 1024 + (size_t)(TSTEPS + 1) * RELEMS * sizeof(float);  // ~125 MB
  const bool fresh = (ws_size >= need);

  alif_init<<<dim3(1), dim3(256), 0, stream>>>(bar);

  void* args[] = {(void*)&u0, (void*)&ext, (void*)&wrec, (void*)&mask, (void*)&sign,
                  (void*)&dtv, (void*)&rbuf, (void*)&out, (void*)&bar};

  const void* fn = fresh ? (const void*)alif_main<true> : (const void*)alif_main<false>;
  hipError_t err = hipLaunchCooperativeKernel(fn, dim3(NBLK), dim3(1024), args, 0, stream);
  if (err != hipSuccess) {
    (void)hipLaunchCooperativeKernel(fn, dim3(NBLK), dim3(256), args, 0, stream);
  }

  alif_readout<<<dim3(TSTEPS * BATCH / 4), dim3(256), 0, stream>>>(
      u0, out, wout, out + OUT_BASE);
}